// Round 12
// baseline (383.343 us; speedup 1.0000x reference)
//
#include <hip/hip_runtime.h>
#include <math.h>

#define FEA   256
#define ATT   64
#define HLAST 10
#define NSTEP 12
#define HDIM  2560
#define BATCH 64
#define BT    768     // BATCH*NSTEP
#define KT_FULL 160   // 5120/32 k-tiles in W
#define KT_HALF 80    // 2560/32
#define NT_G  160     // 2560/16 n-tiles per gate
#define MT_E  48      // 768/16

typedef _Float16 h8_t __attribute__((ext_vector_type(8)));
typedef float    f4_t __attribute__((ext_vector_type(4)));

__device__ __forceinline__ float sigm(float x) { return 1.0f / (1.0f + expf(-x)); }

// ---- pack encoder weights into MFMA B-fragment layout ----
__global__ __launch_bounds__(256) void k_pack_enc(
    const float* __restrict__ W0, const float* __restrict__ W1,
    _Float16* __restrict__ Bp0, _Float16* __restrict__ Bp1)
{
  const int tid = threadIdx.x;
  for (int e = tid; e < 16 * 512; e += 256) {
    const int frag = e >> 9, idx = e & 511, l = idx >> 3, j = idx & 7;
    const int nt = frag >> 1, kt = frag & 1;
    const int k = kt * 32 + (l >> 4) * 8 + j;
    const int n = nt * 16 + (l & 15);
    Bp0[e] = (_Float16)W0[k * 128 + n];
  }
  for (int e = tid; e < 4 * 512; e += 256) {
    const int kt = e >> 9, idx = e & 511, l = idx >> 3, j = idx & 7;
    const int k = kt * 32 + (l >> 4) * 8 + j;
    const int n = l & 15;
    Bp1[e] = (n < HLAST) ? (_Float16)W1[k * HLAST + n] : (_Float16)0.0f;
  }
}

// ---- merged launch 1: enc2 (3072 blocks) + convert first K-half (6400 blocks)
// Interleave: per 37-block group, 12 enc2 + 25 convert (256*37 = 9472 exact).
__global__ __launch_bounds__(256) void k_enc_conv(
    const float* __restrict__ x, const _Float16* __restrict__ Bp0,
    const _Float16* __restrict__ Bp1, const float* __restrict__ b0,
    const float* __restrict__ b1, _Float16* __restrict__ Ep,
    const float* __restrict__ Wf, const float* __restrict__ Wi,
    const float* __restrict__ Wo, const float* __restrict__ Wc,
    _Float16* __restrict__ Wp)
{
  __shared__ __align__(16) _Float16 sA[4][16][136];   // 17408 B (conv needs 16640)
  const int grp = blockIdx.x / 37, r37 = blockIdx.x % 37;
  const int tid = threadIdx.x;

  if (r37 >= 12) {
    // ---- convert role: fp32 W -> fp16 MFMA fragments, kt in [0,80) ----
    float (*tile)[130] = (float(*)[130])(void*)sA;
    const int cid = grp * 25 + (r37 - 12);            // 0..6399
    const int g = cid / 1600;
    const int r = cid % 1600;
    const int kt = r / 20, cb = r % 20;               // cb: 128-col band
    const float* __restrict__ W = (g == 0) ? Wf : (g == 1) ? Wi : (g == 2) ? Wo : Wc;
    const float* src = W + (size_t)(kt * 32) * HDIM + cb * 128;
    #pragma unroll
    for (int s = 0; s < 4; ++s) {
      const int slot = s * 256 + tid;                 // 0..1023
      const int rr = slot >> 5, c4 = slot & 31;       // row, float4-col
      float4 v = *(const float4*)&src[(size_t)rr * HDIM + c4 * 4];
      *(float4*)&tile[rr][c4 * 4] = v;
    }
    __syncthreads();
    const int l = tid & 63, w = tid >> 6;
    const int k0 = (l >> 4) * 8, c16 = l & 15;
    #pragma unroll
    for (int s = 0; s < 2; ++s) {
      const int f = w * 2 + s;                        // fragment 0..7 in band
      h8_t h;
      #pragma unroll
      for (int j = 0; j < 8; ++j) h[j] = (_Float16)tile[k0 + j][f * 16 + c16];
      const int nt = cb * 8 + f;
      *(h8_t*)&Wp[(((size_t)(g * NT_G + nt) * KT_FULL + kt) << 9) + l * 8] = h;
    }
    return;
  }

  // ---- enc2 role: layer1 (K=64,N=128) -> ReLU -> layer2 (K=128,N=16 pad) ----
  const int eid = grp * 12 + r37;                     // 0..3071
  const int l = tid & 63, w = tid >> 6;
  const int bt = eid >> 2;
  const int f0 = (eid & 3) * 64 + w * 16;
  const int rl = l >> 4, cl = l & 15;

  h8_t B0[16];
  #pragma unroll
  for (int q = 0; q < 16; ++q)
    B0[q] = *(const h8_t*)(Bp0 + (q << 9) + l * 8);

  const float* xr = x + ((size_t)bt * FEA + f0 + cl) * ATT + rl * 8;
  h8_t a0, a1;
  {
    float4 v0 = *(const float4*)(xr);
    float4 v1 = *(const float4*)(xr + 4);
    float4 v2 = *(const float4*)(xr + 32);
    float4 v3 = *(const float4*)(xr + 36);
    #pragma unroll
    for (int j = 0; j < 4; ++j) {
      a0[j]     = (_Float16)((const float*)&v0)[j];
      a0[4 + j] = (_Float16)((const float*)&v1)[j];
      a1[j]     = (_Float16)((const float*)&v2)[j];
      a1[4 + j] = (_Float16)((const float*)&v3)[j];
    }
  }
  f4_t acc1[8] = {};
  #pragma unroll
  for (int j = 0; j < 8; ++j) {
    acc1[j] = __builtin_amdgcn_mfma_f32_16x16x32_f16(a0, B0[j * 2 + 0], acc1[j], 0, 0, 0);
    acc1[j] = __builtin_amdgcn_mfma_f32_16x16x32_f16(a1, B0[j * 2 + 1], acc1[j], 0, 0, 0);
  }
  #pragma unroll
  for (int j = 0; j < 8; ++j) {
    const float bj = b0[j * 16 + cl];
    #pragma unroll
    for (int r = 0; r < 4; ++r)
      sA[w][rl * 4 + r][j * 16 + cl] = (_Float16)fmaxf(acc1[j][r] + bj, 0.0f);
  }
  f4_t acc2 = {};
  #pragma unroll
  for (int kt = 0; kt < 4; ++kt) {
    const h8_t a = *(const h8_t*)&sA[w][cl][kt * 32 + rl * 8];
    const h8_t b = *(const h8_t*)(Bp1 + (kt << 9) + l * 8);
    acc2 = __builtin_amdgcn_mfma_f32_16x16x32_f16(a, b, acc2, 0, 0, 0);
  }
  if (cl < HLAST) {
    const float b1v = b1[cl];
    #pragma unroll
    for (int r = 0; r < 4; ++r) {
      const int f = f0 + rl * 4 + r;
      const float val = fmaxf(acc2[r] + b1v, 0.0f);
      const int kf = f * HLAST + cl;
      const int mt = bt >> 4, kt2 = kf >> 5, gp = (kf >> 3) & 3, jj = kf & 7;
      Ep[(((size_t)mt * KT_HALF + kt2) << 9) + (((bt & 15) + 16 * gp) << 3) + jj] =
          (_Float16)val;
    }
  }
}

// ---- merged launch 2: xpre (320 blocks) + convert second K-half (6400 blocks)
__global__ __launch_bounds__(512) void k_xpre_conv(
    const _Float16* __restrict__ Ep, _Float16* __restrict__ Wp,
    const float* __restrict__ bf, const float* __restrict__ bi,
    const float* __restrict__ bo, const float* __restrict__ bc,
    _Float16* __restrict__ Xpre,
    const float* __restrict__ Wf, const float* __restrict__ Wi,
    const float* __restrict__ Wo, const float* __restrict__ Wc)
{
  __shared__ __align__(16) _Float16 sB[2][16 * 512];   // 32 KB (conv needs 16640 B)
  const int bid = blockIdx.x, tid = threadIdx.x;

  if (bid % 21 != 0) {
    // ---- convert role: one 32x128 tile, 512 threads, kt in [80,160) ----
    float (*tile)[130] = (float(*)[130])(void*)sB;
    const int cid = bid - bid / 21 - 1;               // 0..6399
    const int g = cid / 1600;
    const int r = cid % 1600;
    const int kt = 80 + r / 20, cb = r % 20;
    const float* __restrict__ W = (g == 0) ? Wf : (g == 1) ? Wi : (g == 2) ? Wo : Wc;
    const float* src = W + (size_t)(kt * 32) * HDIM + cb * 128;
    #pragma unroll
    for (int s = 0; s < 2; ++s) {
      const int slot = s * 512 + tid;                 // 0..1023
      const int rr = slot >> 5, c4 = slot & 31;
      float4 v = *(const float4*)&src[(size_t)rr * HDIM + c4 * 4];
      *(float4*)&tile[rr][c4 * 4] = v;
    }
    __syncthreads();
    const int l = tid & 63, f = tid >> 6;             // one fragment per wave
    const int k0 = (l >> 4) * 8, c16 = l & 15;
    h8_t h;
    #pragma unroll
    for (int j = 0; j < 8; ++j) h[j] = (_Float16)tile[k0 + j][f * 16 + c16];
    const int nt = cb * 8 + f;
    *(h8_t*)&Wp[(((size_t)(g * NT_G + nt) * KT_FULL + kt) << 9) + l * 8] = h;
    return;
  }

  // ---- xpre role: 4-kt double-buffered stage, 20 chunks ----
  const int rid = bid / 21;                           // 0..319
  const int bx = rid % 40, by = (rid / 40) & 1, bz = rid / 80;
  const int g = bz, mh = by;
  const float* __restrict__ bias = (g == 0) ? bf : (g == 1) ? bi : (g == 2) ? bo : bc;
  const int nt0 = bx * 4;                             // 4 n-tiles = 64 cols
  const int l = tid & 63, w = tid >> 6;
  const int mt0 = mh * 24 + w * 3;                    // 8 waves x 3 mt = 24 mt per half
  const _Float16* Bsrc = Wp + ((size_t)(g * NT_G + nt0) * KT_FULL) * 512 + l * 8;
  const _Float16* Asrc = Ep + ((size_t)mt0 * KT_HALF) * 512 + l * 8;

  f4_t acc[3][4] = {};

  // stage 16 fragments (4 nt x 4 kt): 2 issues per wave
#define STAGE_XPRE(cc, buf)                                                       \
  {                                                                               \
    _Pragma("unroll")                                                             \
    for (int s = 0; s < 2; ++s) {                                                 \
      const int fi = s * 8 + w;                                                   \
      const int jj = fi >> 2, tt = fi & 3;                                        \
      const _Float16* gsrc = Bsrc + ((size_t)jj * KT_FULL + (cc) * 4 + tt) * 512; \
      __builtin_amdgcn_global_load_lds(                                           \
          (const __attribute__((address_space(1))) unsigned int*)(const void*)gsrc, \
          (__attribute__((address_space(3))) unsigned int*)(void*)&sB[buf][fi * 512], \
          16, 0, 0);                                                              \
    }                                                                             \
  }

  STAGE_XPRE(0, 0);
  __syncthreads();
  for (int cc = 0; cc < 20; ++cc) {
    const int buf = cc & 1;
    if (cc < 19) STAGE_XPRE(cc + 1, buf ^ 1);
    #pragma unroll
    for (int t = 0; t < 4; ++t) {
      const int kt = cc * 4 + t;
      h8_t b[4], a[3];
      #pragma unroll
      for (int j = 0; j < 4; ++j)
        b[j] = *(const h8_t*)&sB[buf][(j * 4 + t) * 512 + l * 8];
      #pragma unroll
      for (int i = 0; i < 3; ++i)
        a[i] = *(const h8_t*)(Asrc + ((size_t)i * KT_HALF + kt) * 512);
      #pragma unroll
      for (int i = 0; i < 3; ++i)
        #pragma unroll
        for (int j = 0; j < 4; ++j)
          acc[i][j] = __builtin_amdgcn_mfma_f32_16x16x32_f16(a[i], b[j], acc[i][j], 0, 0, 0);
    }
    __syncthreads();
  }

  const int rl = l >> 4, cl = l & 15;
  const int bn = nt0 * 16;
  #pragma unroll
  for (int j = 0; j < 4; ++j) {
    const int n = bn + j * 16 + cl;
    const float bv = bias[n];
    #pragma unroll
    for (int i = 0; i < 3; ++i)
      #pragma unroll
      for (int r = 0; r < 4; ++r) {
        const int m = (mt0 + i) * 16 + rl * 4 + r;
        Xpre[((size_t)g * BT + m) * HDIM + n] = (_Float16)(acc[i][j][r] + bv);
      }
  }
#undef STAGE_XPRE
}

// ---- fused recurrent step: 1D grid 320 with XCD-pairing remap ----
// Proven round-2/8 body. The remap nt=(bid&7)+8*(bid>>4), mh=(bid>>3)&1 is
// bijective on [0,320) and gives the two mh-twin blocks of each nt (which
// read an IDENTICAL 320KB B-fragment stream) the same bid%8 residue -> same
// XCD -> the second block's B reads hit that XCD's L2 instead of missing to
// L3. Pure index permutation: no sync or cross-launch state changes.
__global__ __launch_bounds__(512) void k_step(
    const _Float16* __restrict__ hP, const _Float16* __restrict__ Wp,
    const _Float16* __restrict__ Xpre, float* __restrict__ cbuf,
    float* __restrict__ hbuf, _Float16* __restrict__ hPn, int tstep)
{
  __shared__ float pre_lds[8][32 * 17];
  const int tid = threadIdx.x, l = tid & 63, w = tid >> 6;
  const int g = w >> 1, kc = w & 1;
  const int bid = blockIdx.x;
  const int nt = (bid & 7) + 8 * (bid >> 4);        // XCD-paired mapping
  const int mh = (bid >> 3) & 1;
  const int kt0 = kc * 40;
  const int dir = tstep & 1;
  const int base = dir ? (kt0 + 39) : kt0;
  const int sgn = dir ? -1 : 1;

  // epilogue operand prefetch (independent of GEMM)
  const int ub = tid >> 4, un = tid & 15;          // 32 rows x 16 cols
  const int brow = mh * 32 + ub;
  const int unf = nt * 16 + un;
  const size_t xr = ((size_t)brow * NSTEP + tstep) * HDIM + unf;
  const float xf = (float)Xpre[xr];
  const float xi = (float)Xpre[(size_t)1 * BT * HDIM + xr];
  const float xo = (float)Xpre[(size_t)2 * BT * HDIM + xr];
  const float xc = (float)Xpre[(size_t)3 * BT * HDIM + xr];
  const size_t ci = (size_t)brow * HDIM + unf;
  const float cold = cbuf[ci];

  const _Float16* Ab = hP + (((size_t)mh * 2 * KT_HALF) << 9) + l * 8;
  const _Float16* Bb = Wp + (((size_t)(g * NT_G + nt) * KT_FULL + KT_HALF) << 9) + l * 8;

  f4_t acc[2] = {};
  // depth-12 B / depth-4 A rolling prefetch, serpentine order
  h8_t bq[12];
  #pragma unroll
  for (int s = 0; s < 12; ++s)
    bq[s] = *(const h8_t*)(Bb + ((size_t)(base + sgn * s) << 9));
  h8_t aq[4][2];
  #pragma unroll
  for (int s = 0; s < 4; ++s)
    #pragma unroll
    for (int i = 0; i < 2; ++i)
      aq[s][i] = *(const h8_t*)(Ab + (((size_t)(i * KT_HALF + base + sgn * s)) << 9));

  #pragma unroll
  for (int it = 0; it < 40; ++it) {
    const int kt = base + sgn * it;
    const h8_t bcur = bq[it % 12];
    const h8_t a0 = aq[it & 3][0], a1 = aq[it & 3][1];
    if (it < 28)
      bq[it % 12] = *(const h8_t*)(Bb + ((size_t)(kt + sgn * 12) << 9));
    if (it < 36) {
      aq[it & 3][0] = *(const h8_t*)(Ab + (((size_t)(0 * KT_HALF + kt + sgn * 4)) << 9));
      aq[it & 3][1] = *(const h8_t*)(Ab + (((size_t)(1 * KT_HALF + kt + sgn * 4)) << 9));
    }
    acc[0] = __builtin_amdgcn_mfma_f32_16x16x32_f16(a0, bcur, acc[0], 0, 0, 0);
    acc[1] = __builtin_amdgcn_mfma_f32_16x16x32_f16(a1, bcur, acc[1], 0, 0, 0);
  }

  float* pl = pre_lds[w];
  const int rl = l >> 4, cl = l & 15;
  #pragma unroll
  for (int i = 0; i < 2; ++i)
    #pragma unroll
    for (int r = 0; r < 4; ++r)
      pl[(i * 16 + rl * 4 + r) * 17 + cl] = acc[i][r];
  __syncthreads();
  {
    const int off = ub * 17 + un;
    float pf = xf, pi_ = xi, po = xo, pc = xc;
    #pragma unroll
    for (int kc2 = 0; kc2 < 2; ++kc2) {
      pf  += pre_lds[0 * 2 + kc2][off];
      pi_ += pre_lds[1 * 2 + kc2][off];
      po  += pre_lds[2 * 2 + kc2][off];
      pc  += pre_lds[3 * 2 + kc2][off];
    }
    const float f = sigm(pf), i_ = sigm(pi_), o = sigm(po), gg = tanhf(pc);
    const float cn = f * cold + i_ * gg;
    cbuf[ci] = cn;
    const float hn = o * tanhf(cn);
    if (tstep == NSTEP - 1) hbuf[ci] = hn;
    const int mt = brow >> 4, kt2 = unf >> 5, gp = (unf >> 3) & 3, j = unf & 7;
    hPn[(((size_t)mt * KT_HALF + kt2) << 9) + ((brow & 15) + 16 * gp) * 8 + j] = (_Float16)hn;
  }
}

// ---- final FC ----
__global__ __launch_bounds__(256) void k_out(
    const float* __restrict__ h, const float* __restrict__ Wfc,
    const float* __restrict__ bfc, float* __restrict__ out)
{
  __shared__ float sW[HLAST * HLAST], sb[HLAST];
  const int t = threadIdx.x;
  if (t < HLAST * HLAST) sW[t] = Wfc[t];
  if (t < HLAST) sb[t] = bfc[t];
  __syncthreads();
  const int idx = blockIdx.x * 256 + t;
  const int j = idx % HLAST;
  const int bf_ = idx / HLAST;
  float a = sb[j];
  #pragma unroll
  for (int k = 0; k < HLAST; ++k)
    a = fmaf(fmaxf(h[(size_t)bf_ * HLAST + k], 0.0f), sW[k * HLAST + j], a);
  out[idx] = a;
}

extern "C" void kernel_launch(void* const* d_in, const int* in_sizes, int n_in,
                              void* d_out, int out_size, void* d_ws, size_t ws_size,
                              hipStream_t stream)
{
  const float* x   = (const float*)d_in[0];
  const float* W0  = (const float*)d_in[1];
  const float* b0  = (const float*)d_in[2];
  const float* W1  = (const float*)d_in[3];
  const float* b1  = (const float*)d_in[4];
  const float* Wf  = (const float*)d_in[5];
  const float* bfp = (const float*)d_in[6];
  const float* Wi  = (const float*)d_in[7];
  const float* bip = (const float*)d_in[8];
  const float* Wo  = (const float*)d_in[9];
  const float* bop = (const float*)d_in[10];
  const float* Wc  = (const float*)d_in[11];
  const float* bcp = (const float*)d_in[12];
  const float* Wfc = (const float*)d_in[13];
  const float* bfc = (const float*)d_in[14];

  char* ws = (char*)d_ws;
  _Float16* Wp = (_Float16*)ws;                       ws += (size_t)4 * NT_G * KT_FULL * 512 * 2;  // 104.9 MB
  _Float16* Ep = (_Float16*)ws;                       ws += (size_t)MT_E * KT_HALF * 512 * 2;      // 3.9 MB
  _Float16* Xpre = (_Float16*)ws;                     ws += (size_t)4 * BT * HDIM * 2;             // 15.7 MB
  float* cbuf  = (float*)ws;                          ws += (size_t)BATCH * HDIM * 4;
  float* hbuf  = (float*)ws;                          ws += (size_t)BATCH * HDIM * 4;
  _Float16* hPa = (_Float16*)ws;                      ws += (size_t)BATCH * HDIM * 2;
  _Float16* hPb = (_Float16*)ws;                      ws += (size_t)BATCH * HDIM * 2;
  _Float16* Bp0 = (_Float16*)ws;                      ws += (size_t)16 * 512 * 2;
  _Float16* Bp1 = (_Float16*)ws;                      ws += (size_t)4 * 512 * 2;

  hipMemsetAsync(cbuf, 0, (size_t)BATCH * HDIM * 4, stream);
  hipMemsetAsync(hPa, 0, (size_t)BATCH * HDIM * 2, stream);

  k_pack_enc<<<1, 256, 0, stream>>>(W0, W1, Bp0, Bp1);
  // merged: enc2 + convert(first K-half).  37*256 = 9472 blocks (12:25 mix).
  k_enc_conv<<<37 * 256, 256, 0, stream>>>(x, Bp0, Bp1, b0, b1, Ep,
                                           Wf, Wi, Wo, Wc, Wp);
  // merged: xpre + convert(second K-half). 21*320 = 6720 blocks (1:20 mix).
  k_xpre_conv<<<21 * 320, 512, 0, stream>>>(Ep, Wp, bfp, bip, bop, bcp, Xpre,
                                            Wf, Wi, Wo, Wc);
  _Float16* hin = hPa;
  _Float16* hout = hPb;
  for (int t = 0; t < NSTEP; ++t) {
    k_step<<<320, 512, 0, stream>>>(hin, Wp, Xpre, cbuf, hbuf, hout, t);
    _Float16* tmp = hin; hin = hout; hout = tmp;
  }
  k_out<<<(BATCH * FEA * HLAST) / 256, 256, 0, stream>>>(hbuf, Wfc, bfc, (float*)d_out);
}

// Round 14
// 374.315 us; speedup vs baseline: 1.0241x; 1.0241x over previous
//
#include <hip/hip_runtime.h>
#include <math.h>

#define FEA   256
#define ATT   64
#define HLAST 10
#define NSTEP 12
#define HDIM  2560
#define BATCH 64
#define BT    768     // BATCH*NSTEP
#define KT_FULL 160   // 5120/32 k-tiles in W
#define KT_HALF 80    // 2560/32
#define NT_G  160     // 2560/16 n-tiles per gate
#define MT_E  48      // 768/16
#define HBUF_ELEMS (BATCH * HDIM)

typedef _Float16 h8_t __attribute__((ext_vector_type(8)));
typedef float    f4_t __attribute__((ext_vector_type(4)));

__device__ __forceinline__ float sigm(float x) { return 1.0f / (1.0f + expf(-x)); }

// ---- pack encoder weights into MFMA B-fragment layout ----
__global__ __launch_bounds__(256) void k_pack_enc(
    const float* __restrict__ W0, const float* __restrict__ W1,
    _Float16* __restrict__ Bp0, _Float16* __restrict__ Bp1)
{
  const int tid = threadIdx.x;
  for (int e = tid; e < 16 * 512; e += 256) {
    const int frag = e >> 9, idx = e & 511, l = idx >> 3, j = idx & 7;
    const int nt = frag >> 1, kt = frag & 1;
    const int k = kt * 32 + (l >> 4) * 8 + j;
    const int n = nt * 16 + (l & 15);
    Bp0[e] = (_Float16)W0[k * 128 + n];
  }
  for (int e = tid; e < 4 * 512; e += 256) {
    const int kt = e >> 9, idx = e & 511, l = idx >> 3, j = idx & 7;
    const int k = kt * 32 + (l >> 4) * 8 + j;
    const int n = l & 15;
    Bp1[e] = (n < HLAST) ? (_Float16)W1[k * HLAST + n] : (_Float16)0.0f;
  }
}

// ---- merged launch 1: enc2 (3072 blocks) + convert first K-half (6400 blocks)
// Interleave: per 37-block group, 12 enc2 + 25 convert (256*37 = 9472 exact).
__global__ __launch_bounds__(256) void k_enc_conv(
    const float* __restrict__ x, const _Float16* __restrict__ Bp0,
    const _Float16* __restrict__ Bp1, const float* __restrict__ b0,
    const float* __restrict__ b1, _Float16* __restrict__ Ep,
    const float* __restrict__ Wf, const float* __restrict__ Wi,
    const float* __restrict__ Wo, const float* __restrict__ Wc,
    _Float16* __restrict__ Wp)
{
  __shared__ __align__(16) _Float16 sA[4][16][136];   // 17408 B (conv needs 16640)
  const int grp = blockIdx.x / 37, r37 = blockIdx.x % 37;
  const int tid = threadIdx.x;

  if (r37 >= 12) {
    // ---- convert role: fp32 W -> fp16 MFMA fragments, kt in [0,80) ----
    float (*tile)[130] = (float(*)[130])(void*)sA;
    const int cid = grp * 25 + (r37 - 12);            // 0..6399
    const int g = cid / 1600;
    const int r = cid % 1600;
    const int kt = r / 20, cb = r % 20;               // cb: 128-col band
    const float* __restrict__ W = (g == 0) ? Wf : (g == 1) ? Wi : (g == 2) ? Wo : Wc;
    const float* src = W + (size_t)(kt * 32) * HDIM + cb * 128;
    #pragma unroll
    for (int s = 0; s < 4; ++s) {
      const int slot = s * 256 + tid;                 // 0..1023
      const int rr = slot >> 5, c4 = slot & 31;       // row, float4-col
      float4 v = *(const float4*)&src[(size_t)rr * HDIM + c4 * 4];
      *(float4*)&tile[rr][c4 * 4] = v;
    }
    __syncthreads();
    const int l = tid & 63, w = tid >> 6;
    const int k0 = (l >> 4) * 8, c16 = l & 15;
    #pragma unroll
    for (int s = 0; s < 2; ++s) {
      const int f = w * 2 + s;                        // fragment 0..7 in band
      h8_t h;
      #pragma unroll
      for (int j = 0; j < 8; ++j) h[j] = (_Float16)tile[k0 + j][f * 16 + c16];
      const int nt = cb * 8 + f;
      *(h8_t*)&Wp[(((size_t)(g * NT_G + nt) * KT_FULL + kt) << 9) + l * 8] = h;
    }
    return;
  }

  // ---- enc2 role: layer1 (K=64,N=128) -> ReLU -> layer2 (K=128,N=16 pad) ----
  const int eid = grp * 12 + r37;                     // 0..3071
  const int l = tid & 63, w = tid >> 6;
  const int bt = eid >> 2;
  const int f0 = (eid & 3) * 64 + w * 16;
  const int rl = l >> 4, cl = l & 15;

  h8_t B0[16];
  #pragma unroll
  for (int q = 0; q < 16; ++q)
    B0[q] = *(const h8_t*)(Bp0 + (q << 9) + l * 8);

  const float* xr = x + ((size_t)bt * FEA + f0 + cl) * ATT + rl * 8;
  h8_t a0, a1;
  {
    float4 v0 = *(const float4*)(xr);
    float4 v1 = *(const float4*)(xr + 4);
    float4 v2 = *(const float4*)(xr + 32);
    float4 v3 = *(const float4*)(xr + 36);
    #pragma unroll
    for (int j = 0; j < 4; ++j) {
      a0[j]     = (_Float16)((const float*)&v0)[j];
      a0[4 + j] = (_Float16)((const float*)&v1)[j];
      a1[j]     = (_Float16)((const float*)&v2)[j];
      a1[4 + j] = (_Float16)((const float*)&v3)[j];
    }
  }
  f4_t acc1[8] = {};
  #pragma unroll
  for (int j = 0; j < 8; ++j) {
    acc1[j] = __builtin_amdgcn_mfma_f32_16x16x32_f16(a0, B0[j * 2 + 0], acc1[j], 0, 0, 0);
    acc1[j] = __builtin_amdgcn_mfma_f32_16x16x32_f16(a1, B0[j * 2 + 1], acc1[j], 0, 0, 0);
  }
  #pragma unroll
  for (int j = 0; j < 8; ++j) {
    const float bj = b0[j * 16 + cl];
    #pragma unroll
    for (int r = 0; r < 4; ++r)
      sA[w][rl * 4 + r][j * 16 + cl] = (_Float16)fmaxf(acc1[j][r] + bj, 0.0f);
  }
  f4_t acc2 = {};
  #pragma unroll
  for (int kt = 0; kt < 4; ++kt) {
    const h8_t a = *(const h8_t*)&sA[w][cl][kt * 32 + rl * 8];
    const h8_t b = *(const h8_t*)(Bp1 + (kt << 9) + l * 8);
    acc2 = __builtin_amdgcn_mfma_f32_16x16x32_f16(a, b, acc2, 0, 0, 0);
  }
  if (cl < HLAST) {
    const float b1v = b1[cl];
    #pragma unroll
    for (int r = 0; r < 4; ++r) {
      const int f = f0 + rl * 4 + r;
      const float val = fmaxf(acc2[r] + b1v, 0.0f);
      const int kf = f * HLAST + cl;
      const int mt = bt >> 4, kt2 = kf >> 5, gp = (kf >> 3) & 3, jj = kf & 7;
      Ep[(((size_t)mt * KT_HALF + kt2) << 9) + (((bt & 15) + 16 * gp) << 3) + jj] =
          (_Float16)val;
    }
  }
}

// ---- merged launch 2: xpre (320 blocks) + convert second K-half (6400 blocks)
__global__ __launch_bounds__(512) void k_xpre_conv(
    const _Float16* __restrict__ Ep, _Float16* __restrict__ Wp,
    const float* __restrict__ bf, const float* __restrict__ bi,
    const float* __restrict__ bo, const float* __restrict__ bc,
    _Float16* __restrict__ Xpre,
    const float* __restrict__ Wf, const float* __restrict__ Wi,
    const float* __restrict__ Wo, const float* __restrict__ Wc)
{
  __shared__ __align__(16) _Float16 sB[2][16 * 512];   // 32 KB (conv needs 16640 B)
  const int bid = blockIdx.x, tid = threadIdx.x;

  if (bid % 21 != 0) {
    // ---- convert role: one 32x128 tile, 512 threads, kt in [80,160) ----
    float (*tile)[130] = (float(*)[130])(void*)sB;
    const int cid = bid - bid / 21 - 1;               // 0..6399
    const int g = cid / 1600;
    const int r = cid % 1600;
    const int kt = 80 + r / 20, cb = r % 20;
    const float* __restrict__ W = (g == 0) ? Wf : (g == 1) ? Wi : (g == 2) ? Wo : Wc;
    const float* src = W + (size_t)(kt * 32) * HDIM + cb * 128;
    #pragma unroll
    for (int s = 0; s < 2; ++s) {
      const int slot = s * 512 + tid;                 // 0..1023
      const int rr = slot >> 5, c4 = slot & 31;
      float4 v = *(const float4*)&src[(size_t)rr * HDIM + c4 * 4];
      *(float4*)&tile[rr][c4 * 4] = v;
    }
    __syncthreads();
    const int l = tid & 63, f = tid >> 6;             // one fragment per wave
    const int k0 = (l >> 4) * 8, c16 = l & 15;
    h8_t h;
    #pragma unroll
    for (int j = 0; j < 8; ++j) h[j] = (_Float16)tile[k0 + j][f * 16 + c16];
    const int nt = cb * 8 + f;
    *(h8_t*)&Wp[(((size_t)(g * NT_G + nt) * KT_FULL + kt) << 9) + l * 8] = h;
    return;
  }

  // ---- xpre role: 4-kt double-buffered stage, 20 chunks ----
  const int rid = bid / 21;                           // 0..319
  const int bx = rid % 40, by = (rid / 40) & 1, bz = rid / 80;
  const int g = bz, mh = by;
  const float* __restrict__ bias = (g == 0) ? bf : (g == 1) ? bi : (g == 2) ? bo : bc;
  const int nt0 = bx * 4;                             // 4 n-tiles = 64 cols
  const int l = tid & 63, w = tid >> 6;
  const int mt0 = mh * 24 + w * 3;                    // 8 waves x 3 mt = 24 mt per half
  const _Float16* Bsrc = Wp + ((size_t)(g * NT_G + nt0) * KT_FULL) * 512 + l * 8;
  const _Float16* Asrc = Ep + ((size_t)mt0 * KT_HALF) * 512 + l * 8;

  f4_t acc[3][4] = {};

  // stage 16 fragments (4 nt x 4 kt): 2 issues per wave
#define STAGE_XPRE(cc, buf)                                                       \
  {                                                                               \
    _Pragma("unroll")                                                             \
    for (int s = 0; s < 2; ++s) {                                                 \
      const int fi = s * 8 + w;                                                   \
      const int jj = fi >> 2, tt = fi & 3;                                        \
      const _Float16* gsrc = Bsrc + ((size_t)jj * KT_FULL + (cc) * 4 + tt) * 512; \
      __builtin_amdgcn_global_load_lds(                                           \
          (const __attribute__((address_space(1))) unsigned int*)(const void*)gsrc, \
          (__attribute__((address_space(3))) unsigned int*)(void*)&sB[buf][fi * 512], \
          16, 0, 0);                                                              \
    }                                                                             \
  }

  STAGE_XPRE(0, 0);
  __syncthreads();
  for (int cc = 0; cc < 20; ++cc) {
    const int buf = cc & 1;
    if (cc < 19) STAGE_XPRE(cc + 1, buf ^ 1);
    #pragma unroll
    for (int t = 0; t < 4; ++t) {
      const int kt = cc * 4 + t;
      h8_t b[4], a[3];
      #pragma unroll
      for (int j = 0; j < 4; ++j)
        b[j] = *(const h8_t*)&sB[buf][(j * 4 + t) * 512 + l * 8];
      #pragma unroll
      for (int i = 0; i < 3; ++i)
        a[i] = *(const h8_t*)(Asrc + ((size_t)i * KT_HALF + kt) * 512);
      #pragma unroll
      for (int i = 0; i < 3; ++i)
        #pragma unroll
        for (int j = 0; j < 4; ++j)
          acc[i][j] = __builtin_amdgcn_mfma_f32_16x16x32_f16(a[i], b[j], acc[i][j], 0, 0, 0);
    }
    __syncthreads();
  }

  const int rl = l >> 4, cl = l & 15;
  const int bn = nt0 * 16;
  #pragma unroll
  for (int j = 0; j < 4; ++j) {
    const int n = bn + j * 16 + cl;
    const float bv = bias[n];
    #pragma unroll
    for (int i = 0; i < 3; ++i)
      #pragma unroll
      for (int r = 0; r < 4; ++r) {
        const int m = (mt0 + i) * 16 + rl * 4 + r;
        Xpre[((size_t)g * BT + m) * HDIM + n] = (_Float16)(acc[i][j][r] + bv);
      }
  }
#undef STAGE_XPRE
}

// ---- fused recurrent step: grid (160 nt, 2 mhalf), 512 thr = 8 waves ----
// Proven round-2/8 body. REPLAY-SAFETY FIX (r13 post-mortem): all
// cross-kernel state is now write-once-per-launch rings (hseq[t], cseq[t])
// instead of ping-pong / read-modify-write buffers. Under graph replay,
// cross-XCD L2 lines can go stale between dispatches; with rings a stale
// line holds the SAME deterministic value from the previous replay (benign),
// whereas ping-pong/RMW staleness delivered a different timestep's value
// (the intermittent 0.049 post-timing failures in r11/r13).
__global__ __launch_bounds__(512) void k_step(
    const _Float16* __restrict__ hP, const _Float16* __restrict__ Wp,
    const _Float16* __restrict__ Xpre, const float* __restrict__ cin,
    float* __restrict__ cout, float* __restrict__ hbuf,
    _Float16* __restrict__ hPn, int tstep)
{
  __shared__ float pre_lds[8][32 * 17];
  const int tid = threadIdx.x, l = tid & 63, w = tid >> 6;
  const int g = w >> 1, kc = w & 1;
  const int nt = blockIdx.x, mh = blockIdx.y;
  const int kt0 = kc * 40;
  const int dir = tstep & 1;
  const int base = dir ? (kt0 + 39) : kt0;
  const int sgn = dir ? -1 : 1;

  // epilogue operand prefetch (independent of GEMM)
  const int ub = tid >> 4, un = tid & 15;          // 32 rows x 16 cols
  const int brow = mh * 32 + ub;
  const int unf = nt * 16 + un;
  const size_t xr = ((size_t)brow * NSTEP + tstep) * HDIM + unf;
  const float xf = (float)Xpre[xr];
  const float xi = (float)Xpre[(size_t)1 * BT * HDIM + xr];
  const float xo = (float)Xpre[(size_t)2 * BT * HDIM + xr];
  const float xc = (float)Xpre[(size_t)3 * BT * HDIM + xr];
  const size_t ci = (size_t)brow * HDIM + unf;
  const float cold = cin[ci];

  const _Float16* Ab = hP + (((size_t)mh * 2 * KT_HALF) << 9) + l * 8;
  const _Float16* Bb = Wp + (((size_t)(g * NT_G + nt) * KT_FULL + KT_HALF) << 9) + l * 8;

  f4_t acc[2] = {};
  // depth-12 B / depth-4 A rolling prefetch, serpentine order
  h8_t bq[12];
  #pragma unroll
  for (int s = 0; s < 12; ++s)
    bq[s] = *(const h8_t*)(Bb + ((size_t)(base + sgn * s) << 9));
  h8_t aq[4][2];
  #pragma unroll
  for (int s = 0; s < 4; ++s)
    #pragma unroll
    for (int i = 0; i < 2; ++i)
      aq[s][i] = *(const h8_t*)(Ab + (((size_t)(i * KT_HALF + base + sgn * s)) << 9));

  #pragma unroll
  for (int it = 0; it < 40; ++it) {
    const int kt = base + sgn * it;
    const h8_t bcur = bq[it % 12];
    const h8_t a0 = aq[it & 3][0], a1 = aq[it & 3][1];
    if (it < 28)
      bq[it % 12] = *(const h8_t*)(Bb + ((size_t)(kt + sgn * 12) << 9));
    if (it < 36) {
      aq[it & 3][0] = *(const h8_t*)(Ab + (((size_t)(0 * KT_HALF + kt + sgn * 4)) << 9));
      aq[it & 3][1] = *(const h8_t*)(Ab + (((size_t)(1 * KT_HALF + kt + sgn * 4)) << 9));
    }
    acc[0] = __builtin_amdgcn_mfma_f32_16x16x32_f16(a0, bcur, acc[0], 0, 0, 0);
    acc[1] = __builtin_amdgcn_mfma_f32_16x16x32_f16(a1, bcur, acc[1], 0, 0, 0);
  }

  float* pl = pre_lds[w];
  const int rl = l >> 4, cl = l & 15;
  #pragma unroll
  for (int i = 0; i < 2; ++i)
    #pragma unroll
    for (int r = 0; r < 4; ++r)
      pl[(i * 16 + rl * 4 + r) * 17 + cl] = acc[i][r];
  __syncthreads();
  {
    const int off = ub * 17 + un;
    float pf = xf, pi_ = xi, po = xo, pc = xc;
    #pragma unroll
    for (int kc2 = 0; kc2 < 2; ++kc2) {
      pf  += pre_lds[0 * 2 + kc2][off];
      pi_ += pre_lds[1 * 2 + kc2][off];
      po  += pre_lds[2 * 2 + kc2][off];
      pc  += pre_lds[3 * 2 + kc2][off];
    }
    const float f = sigm(pf), i_ = sigm(pi_), o = sigm(po), gg = tanhf(pc);
    const float cn = f * cold + i_ * gg;
    cout[ci] = cn;
    const float hn = o * tanhf(cn);
    if (tstep == NSTEP - 1) hbuf[ci] = hn;
    const int mt = brow >> 4, kt2 = unf >> 5, gp = (unf >> 3) & 3, j = unf & 7;
    hPn[(((size_t)mt * KT_HALF + kt2) << 9) + ((brow & 15) + 16 * gp) * 8 + j] = (_Float16)hn;
  }
}

// ---- final FC ----
__global__ __launch_bounds__(256) void k_out(
    const float* __restrict__ h, const float* __restrict__ Wfc,
    const float* __restrict__ bfc, float* __restrict__ out)
{
  __shared__ float sW[HLAST * HLAST], sb[HLAST];
  const int t = threadIdx.x;
  if (t < HLAST * HLAST) sW[t] = Wfc[t];
  if (t < HLAST) sb[t] = bfc[t];
  __syncthreads();
  const int idx = blockIdx.x * 256 + t;
  const int j = idx % HLAST;
  const int bf_ = idx / HLAST;
  float a = sb[j];
  #pragma unroll
  for (int k = 0; k < HLAST; ++k)
    a = fmaf(fmaxf(h[(size_t)bf_ * HLAST + k], 0.0f), sW[k * HLAST + j], a);
  out[idx] = a;
}

extern "C" void kernel_launch(void* const* d_in, const int* in_sizes, int n_in,
                              void* d_out, int out_size, void* d_ws, size_t ws_size,
                              hipStream_t stream)
{
  const float* x   = (const float*)d_in[0];
  const float* W0  = (const float*)d_in[1];
  const float* b0  = (const float*)d_in[2];
  const float* W1  = (const float*)d_in[3];
  const float* b1  = (const float*)d_in[4];
  const float* Wf  = (const float*)d_in[5];
  const float* bfp = (const float*)d_in[6];
  const float* Wi  = (const float*)d_in[7];
  const float* bip = (const float*)d_in[8];
  const float* Wo  = (const float*)d_in[9];
  const float* bop = (const float*)d_in[10];
  const float* Wc  = (const float*)d_in[11];
  const float* bcp = (const float*)d_in[12];
  const float* Wfc = (const float*)d_in[13];
  const float* bfc = (const float*)d_in[14];

  char* ws = (char*)d_ws;
  _Float16* Wp = (_Float16*)ws;                       ws += (size_t)4 * NT_G * KT_FULL * 512 * 2;  // 104.9 MB
  _Float16* Ep = (_Float16*)ws;                       ws += (size_t)MT_E * KT_HALF * 512 * 2;      // 3.9 MB
  _Float16* Xpre = (_Float16*)ws;                     ws += (size_t)4 * BT * HDIM * 2;             // 15.7 MB
  float* hbuf  = (float*)ws;                          ws += (size_t)BATCH * HDIM * 4;
  // write-once-per-launch state rings (replay-safe: stale = identical)
  float* cseq = (float*)ws;                           ws += (size_t)(NSTEP + 1) * HBUF_ELEMS * 4;  // 8.5 MB
  _Float16* hseq = (_Float16*)ws;                     ws += (size_t)(NSTEP + 1) * HBUF_ELEMS * 2;  // 4.3 MB
  _Float16* Bp0 = (_Float16*)ws;                      ws += (size_t)16 * 512 * 2;
  _Float16* Bp1 = (_Float16*)ws;                      ws += (size_t)4 * 512 * 2;

  hipMemsetAsync(cseq, 0, (size_t)HBUF_ELEMS * 4, stream);   // c(0) = 0
  hipMemsetAsync(hseq, 0, (size_t)HBUF_ELEMS * 2, stream);   // h(0) = 0

  k_pack_enc<<<1, 256, 0, stream>>>(W0, W1, Bp0, Bp1);
  // merged: enc2 + convert(first K-half).  37*256 = 9472 blocks (12:25 mix).
  k_enc_conv<<<37 * 256, 256, 0, stream>>>(x, Bp0, Bp1, b0, b1, Ep,
                                           Wf, Wi, Wo, Wc, Wp);
  // merged: xpre + convert(second K-half). 21*320 = 6720 blocks (1:20 mix).
  k_xpre_conv<<<21 * 320, 512, 0, stream>>>(Ep, Wp, bfp, bip, bop, bcp, Xpre,
                                            Wf, Wi, Wo, Wc);
  for (int t = 0; t < NSTEP; ++t) {
    k_step<<<dim3(NT_G, 2), 512, 0, stream>>>(
        hseq + (size_t)t * HBUF_ELEMS, Wp, Xpre,
        cseq + (size_t)t * HBUF_ELEMS, cseq + (size_t)(t + 1) * HBUF_ELEMS,
        hbuf, hseq + (size_t)(t + 1) * HBUF_ELEMS, t);
  }
  k_out<<<(BATCH * FEA * HLAST) / 256, 256, 0, stream>>>(hbuf, Wfc, bfc, (float*)d_out);
}